// Round 1
// baseline (161.112 us; speedup 1.0000x reference)
//
#include <hip/hip_runtime.h>

#define T_DIM 4096
#define B_DIM 16
#define D_DIM 128
#define TILE 64
#define ROWS (TILE + 32)   // 96 rows staged (t0-16 .. t0+79)
#define STRIDE 130         // floats; even -> 8B-aligned rows, column reads 2-way (free)
#define NEGV -1e30f

__global__ __launch_bounds__(256) void lcl_main_kernel(
    const float* __restrict__ mot, const float* __restrict__ aud,
    float* __restrict__ ws)
{
    __shared__ float sm[ROWS * STRIDE];
    __shared__ float sa[ROWS * STRIDE];
    __shared__ float redL[8], redC[8];

    const int tid  = threadIdx.x;
    const int lane = tid & 31;   // lane within 32-group = band offset index
    const int grp  = tid >> 5;   // 0..7
    const int t0   = blockIdx.x * TILE;
    const int b    = blockIdx.y;
    const size_t base = (size_t)b * T_DIM * D_DIM;

    // ---- stage + normalize 96 rows of each tensor into LDS ----
    for (int rid = grp; rid < 2 * ROWS; rid += 8) {
        const int tsel = (rid >= ROWS) ? 1 : 0;
        const int lr   = tsel ? rid - ROWS : rid;
        const int g    = t0 - 16 + lr;
        float4 v = make_float4(0.f, 0.f, 0.f, 0.f);
        if (g >= 0 && g < T_DIM) {
            const float* src = tsel ? aud : mot;
            v = *reinterpret_cast<const float4*>(src + base + (size_t)g * D_DIM + lane * 4);
        }
        float ss = v.x*v.x + v.y*v.y + v.z*v.z + v.w*v.w;
        #pragma unroll
        for (int m = 16; m; m >>= 1) ss += __shfl_xor(ss, m);
        const float inv = 1.0f / fmaxf(sqrtf(ss), 1e-12f);
        float* dst = (tsel ? sa : sm) + lr * STRIDE + lane * 4;
        dst[0] = v.x * inv; dst[1] = v.y * inv;
        dst[2] = v.z * inv; dst[3] = v.w * inv;
    }
    __syncthreads();

    float lossA = 0.f, corrA = 0.f;

    // 128 items per block: 64 t-values x 2 directions; 8 groups -> 16 iters
    for (int it = 0; it < 16; ++it) {
        const int item = it * 8 + grp;      // 0..127
        const int tl   = item & (TILE - 1); // local t
        const int dir  = item >> 6;         // 0: m2a (q=m,k=a), 1: a2m
        const float* q = dir ? sa : sm;
        const float* k = dir ? sm : sa;
        const float2* qp = reinterpret_cast<const float2*>(q + (tl + 16) * STRIDE);
        const float2* kp = reinterpret_cast<const float2*>(k + (tl + lane) * STRIDE);

        float a0 = 0.f, a1 = 0.f, a2 = 0.f, a3 = 0.f;
        #pragma unroll
        for (int c2 = 0; c2 < 64; c2 += 4) {
            float2 q0 = qp[c2+0], k0 = kp[c2+0];
            float2 q1 = qp[c2+1], k1 = kp[c2+1];
            float2 q2 = qp[c2+2], k2 = kp[c2+2];
            float2 q3 = qp[c2+3], k3 = kp[c2+3];
            a0 = fmaf(q0.x, k0.x, fmaf(q0.y, k0.y, a0));
            a1 = fmaf(q1.x, k1.x, fmaf(q1.y, k1.y, a1));
            a2 = fmaf(q2.x, k2.x, fmaf(q2.y, k2.y, a2));
            a3 = fmaf(q3.x, k3.x, fmaf(q3.y, k3.y, a3));
        }
        const float dot = (a0 + a1) + (a2 + a3);

        const int  j     = t0 + tl + lane - 16;     // global key index
        const bool valid = (j >= 0) && (j < T_DIM);
        const bool pos   = valid && (lane >= 12) && (lane < 20); // offsets [-4,3]
        const float logit  = valid ? dot * 10.0f : NEGV;  // /temperature(0.1)
        const float plogit = pos   ? logit       : NEGV;

        float mx = logit, mxp = plogit;
        #pragma unroll
        for (int m = 16; m; m >>= 1) {
            mx  = fmaxf(mx,  __shfl_xor(mx,  m));
            mxp = fmaxf(mxp, __shfl_xor(mxp, m));
        }
        float s  = expf(logit  - mx);   // invalid lanes: exp(-1e30) = 0
        float sp = expf(plogit - mxp);
        #pragma unroll
        for (int m = 16; m; m >>= 1) {
            s  += __shfl_xor(s,  m);
            sp += __shfl_xor(sp, m);
        }
        if (lane == 0) {
            lossA += (mx + logf(s)) - (mxp + logf(sp));
            corrA += (mxp >= mx) ? 1.0f : 0.0f;
        }
    }

    if (lane == 0) { redL[grp] = lossA; redC[grp] = corrA; }
    __syncthreads();
    if (tid == 0) {
        float L = 0.f, C = 0.f;
        #pragma unroll
        for (int i = 0; i < 8; ++i) { L += redL[i]; C += redC[i]; }
        const int bid = b * gridDim.x + blockIdx.x;
        ws[2*bid]   = L;
        ws[2*bid+1] = C;
    }
}

__global__ __launch_bounds__(256) void lcl_final_kernel(
    const float* __restrict__ ws, float* __restrict__ out)
{
    const int tid = threadIdx.x;
    float L = 0.f, C = 0.f;
    for (int i = tid; i < 1024; i += 256) { L += ws[2*i]; C += ws[2*i+1]; }
    #pragma unroll
    for (int m = 32; m; m >>= 1) { L += __shfl_xor(L, m); C += __shfl_xor(C, m); }
    __shared__ float rl[4], rc[4];
    if ((tid & 63) == 0) { rl[tid >> 6] = L; rc[tid >> 6] = C; }
    __syncthreads();
    if (tid == 0) {
        const float Lt = rl[0] + rl[1] + rl[2] + rl[3];
        const float Ct = rc[0] + rc[1] + rc[2] + rc[3];
        out[0] = Lt * (1.0f / 131072.0f);  // / (B * 2T)
        out[1] = Ct * (1.0f / 131072.0f);  // / (2 * T * B)
    }
}

extern "C" void kernel_launch(void* const* d_in, const int* in_sizes, int n_in,
                              void* d_out, int out_size, void* d_ws, size_t ws_size,
                              hipStream_t stream) {
    const float* mot = (const float*)d_in[0];
    const float* aud = (const float*)d_in[1];
    float* out = (float*)d_out;
    float* ws  = (float*)d_ws;   // 1024 blocks x 2 floats = 8 KB

    dim3 grid(T_DIM / TILE, B_DIM);
    lcl_main_kernel<<<grid, 256, 0, stream>>>(mot, aud, ws);
    lcl_final_kernel<<<1, 256, 0, stream>>>(ws, out);
}

// Round 2
// 35.379 us; speedup vs baseline: 4.5539x; 4.5539x over previous
//
#include <hip/hip_runtime.h>

typedef __attribute__((ext_vector_type(8))) short bf16x8;
typedef __attribute__((ext_vector_type(4))) float f32x4;

#define T_DIM 4096
#define B_DIM 16
#define D_DIM 128
#define TILE 64
#define ROWS 96          // t0-16 .. t0+79
#define SROW 136         // bf16 units per row (272 B, 16B-aligned, 2-way banks)
#define LROW 100         // f32 words per logits row (100 mod 32 = 4 -> spread)
#define NEGV -1e30f

static __device__ __forceinline__ unsigned short f2bf(float x) {
    unsigned int u = __float_as_uint(x);
    unsigned int r = (u + 0x7FFFu + ((u >> 16) & 1u)) >> 16;   // RNE
    return (unsigned short)r;
}

__global__ __launch_bounds__(512, 4) void lcl_main(
    const float* __restrict__ mot, const float* __restrict__ aud,
    float* __restrict__ ws)
{
    __shared__ unsigned short sm[ROWS * SROW];
    __shared__ unsigned short sa[ROWS * SROW];
    __shared__ float lg[TILE * LROW];
    __shared__ float redL[8], redC[8];

    const int tid  = threadIdx.x;
    const int lane = tid & 63;
    const int wv   = tid >> 6;     // 0..7
    const int g32  = tid >> 5;     // 0..15 staging group
    const int l32  = tid & 31;
    const int t0   = blockIdx.x * TILE;
    const int b    = blockIdx.y;
    const size_t base = (size_t)b * (T_DIM * D_DIM);

    // ---- stage: normalize (f32) -> bf16 into LDS, 192 rows ----
    for (int rid = g32; rid < 2 * ROWS; rid += 16) {
        const int tsel = (rid >= ROWS) ? 1 : 0;
        const int lr   = tsel ? rid - ROWS : rid;
        const int gt   = t0 - 16 + lr;
        float4 v = make_float4(0.f, 0.f, 0.f, 0.f);
        if (gt >= 0 && gt < T_DIM) {
            const float* src = tsel ? aud : mot;
            v = *reinterpret_cast<const float4*>(src + base + (size_t)gt * D_DIM + l32 * 4);
        }
        float ss = v.x*v.x + v.y*v.y + v.z*v.z + v.w*v.w;
        #pragma unroll
        for (int m = 16; m; m >>= 1) ss += __shfl_xor(ss, m);
        const float inv = 1.0f / fmaxf(sqrtf(ss), 1e-12f);
        unsigned int p0 = (unsigned int)f2bf(v.x * inv) | ((unsigned int)f2bf(v.y * inv) << 16);
        unsigned int p1 = (unsigned int)f2bf(v.z * inv) | ((unsigned int)f2bf(v.w * inv) << 16);
        uint2 pk = make_uint2(p0, p1);
        unsigned short* dst = (tsel ? sa : sm) + lr * SROW + l32 * 4;
        *reinterpret_cast<uint2*>(dst) = pk;
    }

    float lossA = 0.f, corrA = 0.f;

    // wave tiling: mi = M-block (0..3), nj0 = first of 3 N-blocks (0 or 3)
    const int mi  = wv >> 1;
    const int nj0 = (wv & 1) * 3;
    const int fr  = lane & 15;          // fragment row/col
    const int fch = (lane >> 4) * 8;    // k-chunk (bf16 units)

    for (int dir = 0; dir < 2; ++dir) {
        const unsigned short* q = dir ? sa : sm;
        const unsigned short* k = dir ? sm : sa;
        __syncthreads();  // dir0: staging done; dir1: reduce0 done (lg free)

        // ---- banded GEMM: C[64][96] = q[16..79] . k[0..95]^T ----
        f32x4 acc0 = {0.f,0.f,0.f,0.f}, acc1 = acc0, acc2 = acc0;
        const unsigned short* qrow = q + (mi * 16 + 16 + fr) * SROW + fch;
        const unsigned short* k0   = k + ((nj0 + 0) * 16 + fr) * SROW + fch;
        const unsigned short* k1   = k + ((nj0 + 1) * 16 + fr) * SROW + fch;
        const unsigned short* k2   = k + ((nj0 + 2) * 16 + fr) * SROW + fch;
        #pragma unroll
        for (int ks = 0; ks < 4; ++ks) {
            bf16x8 af = *reinterpret_cast<const bf16x8*>(qrow + ks * 32);
            bf16x8 b0 = *reinterpret_cast<const bf16x8*>(k0   + ks * 32);
            bf16x8 b1 = *reinterpret_cast<const bf16x8*>(k1   + ks * 32);
            bf16x8 b2 = *reinterpret_cast<const bf16x8*>(k2   + ks * 32);
            acc0 = __builtin_amdgcn_mfma_f32_16x16x32_bf16(af, b0, acc0, 0, 0, 0);
            acc1 = __builtin_amdgcn_mfma_f32_16x16x32_bf16(af, b1, acc1, 0, 0, 0);
            acc2 = __builtin_amdgcn_mfma_f32_16x16x32_bf16(af, b2, acc2, 0, 0, 0);
        }
        // C/D layout: col = lane&15, row = (lane>>4)*4 + reg
        const int crow = mi * 16 + (lane >> 4) * 4;
        #pragma unroll
        for (int r = 0; r < 4; ++r) {
            lg[(crow + r) * LROW + (nj0 + 0) * 16 + fr] = acc0[r];
            lg[(crow + r) * LROW + (nj0 + 1) * 16 + fr] = acc1[r];
            lg[(crow + r) * LROW + (nj0 + 2) * 16 + fr] = acc2[r];
        }
        __syncthreads();

        // ---- band reduction: 64 items, 8 per wave, 8 lanes per item ----
        const int tl = wv * 8 + (lane >> 3);
        const int sl = lane & 7;
        float lo[4], lp[4];
        float mx = NEGV, mxp = NEGV;
        #pragma unroll
        for (int c = 0; c < 4; ++c) {
            const int kk = sl * 4 + c;                 // 0..31, off = kk-16
            const float val = lg[tl * LROW + tl + kk];
            const int  jg    = t0 + tl + kk - 16;
            const bool valid = (jg >= 0) && (jg < T_DIM);
            const bool pos   = valid && (kk >= 12) && (kk < 20);
            lo[c] = valid ? val * 10.0f : NEGV;
            lp[c] = pos   ? lo[c]       : NEGV;
            mx  = fmaxf(mx,  lo[c]);
            mxp = fmaxf(mxp, lp[c]);
        }
        #pragma unroll
        for (int m = 4; m; m >>= 1) {
            mx  = fmaxf(mx,  __shfl_xor(mx,  m));
            mxp = fmaxf(mxp, __shfl_xor(mxp, m));
        }
        float s = 0.f, sp = 0.f;
        #pragma unroll
        for (int c = 0; c < 4; ++c) {
            s  += __expf(lo[c] - mx);
            sp += __expf(lp[c] - mxp);
        }
        #pragma unroll
        for (int m = 4; m; m >>= 1) {
            s  += __shfl_xor(s,  m);
            sp += __shfl_xor(sp, m);
        }
        if (sl == 0) {
            lossA += (mx + logf(s)) - (mxp + logf(sp));
            corrA += (mxp >= mx) ? 1.0f : 0.0f;
        }
    }

    // ---- block reduction of partials ----
    #pragma unroll
    for (int m = 32; m; m >>= 1) {
        lossA += __shfl_xor(lossA, m);
        corrA += __shfl_xor(corrA, m);
    }
    if (lane == 0) { redL[wv] = lossA; redC[wv] = corrA; }
    __syncthreads();
    if (tid == 0) {
        float L = 0.f, C = 0.f;
        #pragma unroll
        for (int i = 0; i < 8; ++i) { L += redL[i]; C += redC[i]; }
        const int bid = b * gridDim.x + blockIdx.x;
        ws[2*bid]   = L;
        ws[2*bid+1] = C;
    }
}

__global__ __launch_bounds__(256) void lcl_final(
    const float* __restrict__ ws, float* __restrict__ out)
{
    const int tid = threadIdx.x;
    float L = 0.f, C = 0.f;
    for (int i = tid; i < 1024; i += 256) { L += ws[2*i]; C += ws[2*i+1]; }
    #pragma unroll
    for (int m = 32; m; m >>= 1) { L += __shfl_xor(L, m); C += __shfl_xor(C, m); }
    __shared__ float rl[4], rc[4];
    if ((tid & 63) == 0) { rl[tid >> 6] = L; rc[tid >> 6] = C; }
    __syncthreads();
    if (tid == 0) {
        const float Lt = rl[0] + rl[1] + rl[2] + rl[3];
        const float Ct = rc[0] + rc[1] + rc[2] + rc[3];
        out[0] = Lt * (1.0f / 131072.0f);   // / (B * 2T)
        out[1] = Ct * (1.0f / 131072.0f);   // / (2 * T * B)
    }
}

extern "C" void kernel_launch(void* const* d_in, const int* in_sizes, int n_in,
                              void* d_out, int out_size, void* d_ws, size_t ws_size,
                              hipStream_t stream) {
    const float* mot = (const float*)d_in[0];
    const float* aud = (const float*)d_in[1];
    float* out = (float*)d_out;
    float* ws  = (float*)d_ws;   // 1024 blocks x 2 floats = 8 KB

    dim3 grid(T_DIM / TILE, B_DIM);
    lcl_main<<<grid, 512, 0, stream>>>(mot, aud, ws);
    lcl_final<<<1, 256, 0, stream>>>(ws, out);
}

// Round 3
// 33.511 us; speedup vs baseline: 4.8077x; 1.0557x over previous
//
#include <hip/hip_runtime.h>

typedef __attribute__((ext_vector_type(8))) short bf16x8;
typedef __attribute__((ext_vector_type(4))) float f32x4;

#define T_DIM 4096
#define B_DIM 16
#define D_DIM 128
#define TILE 64
#define ROWS 96          // staged rows: t0-16 .. t0+79
#define SROW 136         // bf16 units per row (272 B, 16B-aligned)
#define NEGV -1e30f

static __device__ __forceinline__ unsigned short f2bf(float x) {
    unsigned int u = __float_as_uint(x);
    unsigned int r = (u + 0x7FFFu + ((u >> 16) & 1u)) >> 16;   // RNE
    return (unsigned short)r;
}

__global__ __launch_bounds__(512, 6) void lcl_main(
    const float* __restrict__ mot, const float* __restrict__ aud,
    float* __restrict__ ws)
{
    __shared__ unsigned short sm[ROWS * SROW];
    __shared__ unsigned short sa[ROWS * SROW];
    __shared__ float redL[8], redC[8];

    const int tid  = threadIdx.x;
    const int lane = tid & 63;
    const int wv   = tid >> 6;     // 0..7
    const int g32  = tid >> 5;     // 0..15 staging group
    const int l32  = tid & 31;
    const int t0   = blockIdx.x * TILE;
    const int b    = blockIdx.y;
    const size_t base = (size_t)b * (T_DIM * D_DIM);

    // ---- stage: normalize (f32) -> bf16 into LDS, 192 rows ----
    for (int rid = g32; rid < 2 * ROWS; rid += 16) {
        const int tsel = (rid >= ROWS) ? 1 : 0;
        const int lr   = tsel ? rid - ROWS : rid;
        const int gt   = t0 - 16 + lr;
        float4 v = make_float4(0.f, 0.f, 0.f, 0.f);
        if (gt >= 0 && gt < T_DIM) {
            const float* src = tsel ? aud : mot;
            v = *reinterpret_cast<const float4*>(src + base + (size_t)gt * D_DIM + l32 * 4);
        }
        float ss = v.x*v.x + v.y*v.y + v.z*v.z + v.w*v.w;
        #pragma unroll
        for (int m = 16; m; m >>= 1) ss += __shfl_xor(ss, m);
        const float inv = 1.0f / fmaxf(sqrtf(ss), 1e-12f);
        unsigned int p0 = (unsigned int)f2bf(v.x * inv) | ((unsigned int)f2bf(v.y * inv) << 16);
        unsigned int p1 = (unsigned int)f2bf(v.z * inv) | ((unsigned int)f2bf(v.w * inv) << 16);
        uint2 pk = make_uint2(p0, p1);
        unsigned short* dst = (tsel ? sa : sm) + lr * SROW + l32 * 4;
        *reinterpret_cast<uint2*>(dst) = pk;
    }
    __syncthreads();

    // ---- per-wave task: dir = wv>>2, mi = wv&3 ----
    // wave computes q rows [mi*16+16 .. +15] x k blocks {mi, mi+1, mi+2}
    const int dir = wv >> 2;
    const int mi  = wv & 3;
    const unsigned short* q = dir ? sa : sm;
    const unsigned short* k = dir ? sm : sa;

    const int fr  = lane & 15;          // fragment row/col
    const int fch = (lane >> 4) * 8;    // k-chunk (bf16 units)

    f32x4 acc0 = {0.f,0.f,0.f,0.f}, acc1 = acc0, acc2 = acc0;
    const unsigned short* qrow = q + (mi * 16 + 16 + fr) * SROW + fch;
    const unsigned short* k0   = k + ((mi + 0) * 16 + fr) * SROW + fch;
    const unsigned short* k1   = k + ((mi + 1) * 16 + fr) * SROW + fch;
    const unsigned short* k2   = k + ((mi + 2) * 16 + fr) * SROW + fch;
    #pragma unroll
    for (int ks = 0; ks < 4; ++ks) {
        bf16x8 af = *reinterpret_cast<const bf16x8*>(qrow + ks * 32);
        bf16x8 b0 = *reinterpret_cast<const bf16x8*>(k0   + ks * 32);
        bf16x8 b1 = *reinterpret_cast<const bf16x8*>(k1   + ks * 32);
        bf16x8 b2 = *reinterpret_cast<const bf16x8*>(k2   + ks * 32);
        acc0 = __builtin_amdgcn_mfma_f32_16x16x32_bf16(af, b0, acc0, 0, 0, 0);
        acc1 = __builtin_amdgcn_mfma_f32_16x16x32_bf16(af, b1, acc1, 0, 0, 0);
        acc2 = __builtin_amdgcn_mfma_f32_16x16x32_bf16(af, b2, acc2, 0, 0, 0);
    }

    // ---- in-register band reduction ----
    // C/D layout: col = lane&15 (k row within block), row = (lane>>4)*4 + reg.
    // Band member kk = a*16 + col16 - crow; kk in [0,32).
    //   a=1: always in band (kk0 = 16+col16-crow in [1,31]).
    //   a=0 iff col16>=crow; a=2 iff col16<crow (exactly one).
    const int g     = lane >> 4;
    const int col16 = lane & 15;
    float lossW = 0.f, corrW = 0.f;
    #pragma unroll
    for (int r = 0; r < 4; ++r) {
        const int  crow = g * 4 + r;
        const int  kk0  = 16 + col16 - crow;
        const int  j0   = t0 + mi * 16 + col16;                 // a=1 key index
        const bool val0 = (j0 >= 0) && (j0 < T_DIM);
        const bool sel0 = (col16 >= crow);
        const float v1  = sel0 ? acc0[r] : acc2[r];
        const int  kk1  = sel0 ? (col16 - crow) : (32 + col16 - crow);
        const int  j1   = t0 - 16 + (mi + (sel0 ? 0 : 2)) * 16 + col16;
        const bool val1 = (j1 >= 0) && (j1 < T_DIM);
        const float l0  = val0 ? acc1[r] * 10.0f : NEGV;
        const float l1  = val1 ? v1      * 10.0f : NEGV;
        const float p0  = (val0 && kk0 >= 12 && kk0 < 20) ? l0 : NEGV;
        const float p1  = (val1 && kk1 >= 12 && kk1 < 20) ? l1 : NEGV;

        float mx  = fmaxf(l0, l1);
        float mxp = fmaxf(p0, p1);
        #pragma unroll
        for (int m = 8; m; m >>= 1) {
            mx  = fmaxf(mx,  __shfl_xor(mx,  m));
            mxp = fmaxf(mxp, __shfl_xor(mxp, m));
        }
        float s  = __expf(l0 - mx)  + __expf(l1 - mx);
        float sp = __expf(p0 - mxp) + __expf(p1 - mxp);
        #pragma unroll
        for (int m = 8; m; m >>= 1) {
            s  += __shfl_xor(s,  m);
            sp += __shfl_xor(sp, m);
        }
        if (col16 == 0) {
            lossW += (mx + logf(s)) - (mxp + logf(sp));
            corrW += (mxp >= mx) ? 1.0f : 0.0f;
        }
    }

    // wave partials live at lanes 0,16,32,48 -> sum to lane 0
    lossW += __shfl_xor(lossW, 16);
    corrW += __shfl_xor(corrW, 16);
    lossW += __shfl_xor(lossW, 32);
    corrW += __shfl_xor(corrW, 32);
    if (lane == 0) { redL[wv] = lossW; redC[wv] = corrW; }
    __syncthreads();
    if (tid == 0) {
        float L = 0.f, C = 0.f;
        #pragma unroll
        for (int i = 0; i < 8; ++i) { L += redL[i]; C += redC[i]; }
        const int bid = b * gridDim.x + blockIdx.x;
        ws[2*bid]   = L;
        ws[2*bid+1] = C;
    }
}

__global__ __launch_bounds__(256) void lcl_final(
    const float* __restrict__ ws, float* __restrict__ out)
{
    const int tid = threadIdx.x;
    float L = 0.f, C = 0.f;
    for (int i = tid; i < 1024; i += 256) { L += ws[2*i]; C += ws[2*i+1]; }
    #pragma unroll
    for (int m = 32; m; m >>= 1) { L += __shfl_xor(L, m); C += __shfl_xor(C, m); }
    __shared__ float rl[4], rc[4];
    if ((tid & 63) == 0) { rl[tid >> 6] = L; rc[tid >> 6] = C; }
    __syncthreads();
    if (tid == 0) {
        const float Lt = rl[0] + rl[1] + rl[2] + rl[3];
        const float Ct = rc[0] + rc[1] + rc[2] + rc[3];
        out[0] = Lt * (1.0f / 131072.0f);   // / (B * 2T)
        out[1] = Ct * (1.0f / 131072.0f);   // / (2 * T * B)
    }
}

extern "C" void kernel_launch(void* const* d_in, const int* in_sizes, int n_in,
                              void* d_out, int out_size, void* d_ws, size_t ws_size,
                              hipStream_t stream) {
    const float* mot = (const float*)d_in[0];
    const float* aud = (const float*)d_in[1];
    float* out = (float*)d_out;
    float* ws  = (float*)d_ws;   // 1024 blocks x 2 floats = 8 KB

    dim3 grid(T_DIM / TILE, B_DIM);
    lcl_main<<<grid, 512, 0, stream>>>(mot, aud, ws);
    lcl_final<<<1, 256, 0, stream>>>(ws, out);
}